// Round 8
// baseline (19421.236 us; speedup 1.0000x reference)
//
#include <hip/hip_runtime.h>

// Seq2Seq LSTM (E=256,H=512,B=1024,S=128,T=128). FP32 in/out (verified r6).
// Round 8: single persistent kernel, 512 blocks (2/CU co-resident), software
// grid barrier per step (threadfence + agent-scope monotonic counter).
// c-state in registers; h ping-pong via global bf16 hi/lo planes; 3-term
// split-bf16 MFMA GEMM (fp32-equivalent); FC inlined on blocks 0..127.

typedef unsigned short u16;
typedef __attribute__((ext_vector_type(8))) short short8;
typedef __attribute__((ext_vector_type(4))) float floatx4;

#define NBLK 512

__device__ __forceinline__ float bf2f(u16 s) {
  union { unsigned int u; float f; } v; v.u = ((unsigned int)s) << 16; return v.f;
}
__device__ __forceinline__ u16 f2bf(float x) {
  union { float f; unsigned int u; } v; v.f = x;
  unsigned int r = (v.u + 0x7FFFu + ((v.u >> 16) & 1u)) >> 16;
  return (u16)r;
}
__device__ __forceinline__ void split2(float x, u16* hi, u16* lo) {
  u16 h = f2bf(x);
  *hi = h;
  *lo = f2bf(x - bf2f(h));
}
__device__ __forceinline__ float sigm(float x) { return 1.0f / (1.0f + expf(-x)); }

// ---------------------------------------------------------------- prep ------
__global__ __launch_bounds__(256) void prep_m(
    const float* __restrict__ e_wih, const float* __restrict__ e_whh,
    const float* __restrict__ e_bih, const float* __restrict__ e_bhh,
    const float* __restrict__ d_wih, const float* __restrict__ d_whh,
    const float* __restrict__ d_bih, const float* __restrict__ d_bhh,
    const float* __restrict__ emb, const float* __restrict__ dec_emb,
    const float* __restrict__ fc_w, const float* __restrict__ fc_b,
    u16* __restrict__ WhiE, u16* __restrict__ WloE,
    u16* __restrict__ WhiD, u16* __restrict__ WloD,
    float* __restrict__ bcE, float* __restrict__ bcD,
    u16* __restrict__ eHiE, u16* __restrict__ eLoE,
    u16* __restrict__ eHiD, u16* __restrict__ eLoD,
    float* __restrict__ fwT, float* __restrict__ fcb,
    u16* __restrict__ hHi, u16* __restrict__ hLo,
    unsigned* __restrict__ cnt, float* __restrict__ out) {
  int idx0 = blockIdx.x * blockDim.x + threadIdx.x;
  int stride = gridDim.x * blockDim.x;
  if (idx0 == 0) *cnt = 0u;
  for (int i = idx0; i < 2048 * 768; i += stride) {
    int rr = i / 768, k = i - rr * 768;
    int j = rr >> 2, g = rr & 3;
    int orig = g * 512 + j;  // reference gate order i,f,g,o
    float we = (k < 256) ? e_wih[orig * 256 + k] : e_whh[orig * 512 + (k - 256)];
    float wd = (k < 256) ? d_wih[orig * 256 + k] : d_whh[orig * 512 + (k - 256)];
    split2(we, &WhiE[i], &WloE[i]);
    split2(wd, &WhiD[i], &WloD[i]);
  }
  for (int i = idx0; i < 2048; i += stride) {
    int j = i >> 2, g = i & 3, orig = g * 512 + j;
    bcE[i] = e_bih[orig] + e_bhh[orig];
    bcD[i] = d_bih[orig] + d_bhh[orig];
  }
  for (int i = idx0; i < 128 * 256; i += stride) {
    split2(emb[i], &eHiE[i], &eLoE[i]);
    split2(dec_emb[i], &eHiD[i], &eLoD[i]);
  }
  for (int i = idx0; i < 128 * 512; i += stride) {
    int v = i >> 9, k = i & 511;
    fwT[k * 128 + v] = fc_w[i];
  }
  for (int i = idx0; i < 128; i += stride) fcb[i] = fc_b[i];
  for (int i = idx0; i < 1024 * 512; i += stride) { hHi[i] = 0; hLo[i] = 0; }
  for (int i = idx0; i < 1024 * 128; i += stride)
    out[(i >> 7) * 16384 + (i & 127)] = 0.0f;  // out[:,0,:] = 0
}

// ----------------------------------------------------- persistent kernel ----
// 512 blocks: bid -> n0 = (bid&31)*64 (interleaved gate cols), m0 = (bid>>5)*64.
// 255 steps inside one dispatch, grid barrier between steps.
__global__ __launch_bounds__(256, 2) void seq_persist(
    const u16* __restrict__ eHiE, const u16* __restrict__ eLoE,
    const u16* __restrict__ eHiD, const u16* __restrict__ eLoD,
    const int* __restrict__ src, const int* __restrict__ tgt,
    const u16* __restrict__ WhiE, const u16* __restrict__ WloE,
    const u16* __restrict__ WhiD, const u16* __restrict__ WloD,
    const float* __restrict__ bcE, const float* __restrict__ bcD,
    const float* __restrict__ fwT, const float* __restrict__ fcb,
    u16* __restrict__ hHiA, u16* __restrict__ hLoA,
    u16* __restrict__ hHiB, u16* __restrict__ hLoB,
    float* __restrict__ out, unsigned* __restrict__ cnt) {
  __shared__ __align__(16) unsigned char smem[20480];
  __shared__ int sidx[64];
  short* sAhi = (short*)(smem);
  short* sAlo = (short*)(smem + 5120);
  short* sBhi = (short*)(smem + 10240);
  short* sBlo = (short*)(smem + 15360);
  const int tid = threadIdx.x;
  const int bid = blockIdx.x;
  const int n0 = (bid & 31) * 64;
  const int m0 = (bid >> 5) * 64;

  const int rs = tid >> 2;
  const int qo = (tid & 3) * 8;
  const int so = rs * 40 + qo;

  const int lane = tid & 63;
  const int wv = tid >> 6;
  const int wm = wv & 1, wn = wv >> 1;
  const int lr = lane & 15, lq = lane >> 4;
  const int ra0 = wm * 32 + lr, ra1 = ra0 + 16;
  const int rb0 = wn * 32 + lr, rb1 = rb0 + 16;
  const int oa0 = ra0 * 40 + lq * 8, oa1 = ra1 * 40 + lq * 8;
  const int ob0 = rb0 * 40 + lq * 8, ob1 = rb1 * 40 + lq * 8;

  float cst[4] = {0.f, 0.f, 0.f, 0.f};  // cell state lives in registers

  u16* hiIn = hHiA; u16* loIn = hLoA;
  u16* hiOut = hHiB; u16* loOut = hLoB;

  for (int step = 0; step < 255; ++step) {
    const bool enc = (step < 128);
    const int t = enc ? step : (step - 128);
    const int* idx = enc ? src : tgt;
    const u16* eHi = enc ? eHiE : eHiD;
    const u16* eLo = enc ? eLoE : eLoD;
    const u16* Whi = enc ? WhiE : WhiD;
    const u16* Wlo = enc ? WloE : WloD;
    const float* bc = enc ? bcE : bcD;

    if (tid < 64) sidx[tid] = idx[(m0 + tid) * 128 + t];
    __syncthreads();

    const u16* aHiE = eHi + sidx[rs] * 256 + qo;
    const u16* aLoE = eLo + sidx[rs] * 256 + qo;
    const u16* aHiH = hiIn + (m0 + rs) * 512 + qo;
    const u16* aLoH = loIn + (m0 + rs) * 512 + qo;
    const u16* bHi = Whi + (n0 + rs) * 768 + qo;
    const u16* bLo = Wlo + (n0 + rs) * 768 + qo;

    floatx4 acc00 = {0.f, 0.f, 0.f, 0.f}, acc01 = {0.f, 0.f, 0.f, 0.f};
    floatx4 acc10 = {0.f, 0.f, 0.f, 0.f}, acc11 = {0.f, 0.f, 0.f, 0.f};

    short8 vah = *(const short8*)aHiE;
    short8 val = *(const short8*)aLoE;
    short8 vbh = *(const short8*)bHi;
    short8 vbl = *(const short8*)bLo;

    for (int kk = 0; kk < 24; ++kk) {
      *(short8*)&sAhi[so] = vah;
      *(short8*)&sAlo[so] = val;
      *(short8*)&sBhi[so] = vbh;
      *(short8*)&sBlo[so] = vbl;
      __syncthreads();
      if (kk < 23) {
        const int k1 = (kk + 1) * 32;
        if (k1 < 256) {
          vah = *(const short8*)(aHiE + k1);
          val = *(const short8*)(aLoE + k1);
        } else {
          vah = *(const short8*)(aHiH + (k1 - 256));
          val = *(const short8*)(aLoH + (k1 - 256));
        }
        vbh = *(const short8*)(bHi + k1);
        vbl = *(const short8*)(bLo + k1);
      }
      short8 ah0 = *(const short8*)&sAhi[oa0];
      short8 ah1 = *(const short8*)&sAhi[oa1];
      short8 al0 = *(const short8*)&sAlo[oa0];
      short8 al1 = *(const short8*)&sAlo[oa1];
      short8 bh0 = *(const short8*)&sBhi[ob0];
      short8 bh1 = *(const short8*)&sBhi[ob1];
      short8 bl0 = *(const short8*)&sBlo[ob0];
      short8 bl1 = *(const short8*)&sBlo[ob1];
      acc00 = __builtin_amdgcn_mfma_f32_16x16x32_bf16(al0, bh0, acc00, 0, 0, 0);
      acc00 = __builtin_amdgcn_mfma_f32_16x16x32_bf16(ah0, bl0, acc00, 0, 0, 0);
      acc00 = __builtin_amdgcn_mfma_f32_16x16x32_bf16(ah0, bh0, acc00, 0, 0, 0);
      acc01 = __builtin_amdgcn_mfma_f32_16x16x32_bf16(al0, bh1, acc01, 0, 0, 0);
      acc01 = __builtin_amdgcn_mfma_f32_16x16x32_bf16(ah0, bl1, acc01, 0, 0, 0);
      acc01 = __builtin_amdgcn_mfma_f32_16x16x32_bf16(ah0, bh1, acc01, 0, 0, 0);
      acc10 = __builtin_amdgcn_mfma_f32_16x16x32_bf16(al1, bh0, acc10, 0, 0, 0);
      acc10 = __builtin_amdgcn_mfma_f32_16x16x32_bf16(ah1, bl0, acc10, 0, 0, 0);
      acc10 = __builtin_amdgcn_mfma_f32_16x16x32_bf16(ah1, bh0, acc10, 0, 0, 0);
      acc11 = __builtin_amdgcn_mfma_f32_16x16x32_bf16(al1, bh1, acc11, 0, 0, 0);
      acc11 = __builtin_amdgcn_mfma_f32_16x16x32_bf16(ah1, bl1, acc11, 0, 0, 0);
      acc11 = __builtin_amdgcn_mfma_f32_16x16x32_bf16(ah1, bh1, acc11, 0, 0, 0);
      __syncthreads();
    }

    // gates -> LDS fp32 (stride 68; reuses tile memory)
    float* gl = (float*)smem;
    const int rowb = wm * 32 + lq * 4;
    const int colb = wn * 32 + lr;
#pragma unroll
    for (int j = 0; j < 4; ++j) {
      gl[(rowb + j) * 68 + colb] = acc00[j];
      gl[(rowb + j) * 68 + colb + 16] = acc01[j];
      gl[(rowb + 16 + j) * 68 + colb] = acc10[j];
      gl[(rowb + 16 + j) * 68 + colb + 16] = acc11[j];
    }
    __syncthreads();

    // fused LSTM cell; c in registers (fixed (row,unit) mapping across steps)
#pragma unroll
    for (int ii = 0; ii < 4; ++ii) {
      int pp = ii * 256 + tid;
      int row = pp >> 4;
      int u = pp & 15;
      const float* gp = gl + row * 68 + u * 4;
      const float* bp = bc + n0 + u * 4;
      float gi = gp[0] + bp[0];
      float gf = gp[1] + bp[1];
      float gg = gp[2] + bp[2];
      float go = gp[3] + bp[3];
      float cn = sigm(gf) * cst[ii] + sigm(gi) * tanhf(gg);
      cst[ii] = cn;
      float h = sigm(go) * tanhf(cn);
      u16 hi, lo;
      split2(h, &hi, &lo);
      int ci = (m0 + row) * 512 + ((n0 >> 2) + u);
      hiOut[ci] = hi;
      loOut[ci] = lo;
    }

    // ---- grid barrier (device-scope; handles cross-XCD L2 non-coherence) ----
    __syncthreads();  // drains this block's vmcnt -> stores are in L2
    if (tid == 0) {
      __threadfence();  // release: wbl2 (flush this XCD's L2 to LLC)
      __hip_atomic_fetch_add(cnt, 1u, __ATOMIC_RELAXED, __HIP_MEMORY_SCOPE_AGENT);
      const unsigned need = (unsigned)(step + 1) * (unsigned)NBLK;
      while (__hip_atomic_load(cnt, __ATOMIC_RELAXED, __HIP_MEMORY_SCOPE_AGENT) < need)
        __builtin_amdgcn_s_sleep(2);
      __threadfence();  // acquire: inv (invalidate local L2/L1)
    }
    __syncthreads();

    // ---- FC for decoder steps: blocks 0..127, 8 batch rows each ----
    if (!enc && bid < 128) {
      float* smH = (float*)smem;
      const int b0 = bid * 8;
      {
        int o = b0 * 512 + tid * 16;
        short8 vh = *(const short8*)(hiOut + o);
        short8 vl = *(const short8*)(loOut + o);
        short8 vh2 = *(const short8*)(hiOut + o + 8);
        short8 vl2 = *(const short8*)(loOut + o + 8);
        float* d = &smH[tid * 16];
#pragma unroll
        for (int j = 0; j < 8; ++j) d[j] = bf2f((u16)vh[j]) + bf2f((u16)vl[j]);
#pragma unroll
        for (int j = 0; j < 8; ++j) d[8 + j] = bf2f((u16)vh2[j]) + bf2f((u16)vl2[j]);
      }
      __syncthreads();
      const int v = tid & 127;
      const int half = tid >> 7;
      float facc[8];
#pragma unroll
      for (int r0 = 0; r0 < 8; ++r0) facc[r0] = 0.0f;
      const int kbase = half * 256;
      for (int k = kbase; k < kbase + 256; ++k) {
        float w = fwT[k * 128 + v];
#pragma unroll
        for (int r0 = 0; r0 < 8; ++r0) facc[r0] += smH[r0 * 512 + k] * w;
      }
      __syncthreads();
      float* red = smH;
#pragma unroll
      for (int r0 = 0; r0 < 8; ++r0) red[half * 1024 + r0 * 128 + v] = facc[r0];
      __syncthreads();
      if (half == 0) {
        float bias = fcb[v];
#pragma unroll
        for (int r0 = 0; r0 < 8; ++r0) {
          float sum = red[r0 * 128 + v] + red[1024 + r0 * 128 + v] + bias;
          out[(b0 + r0) * 16384 + (t + 1) * 128 + v] = sum;
        }
      }
      __syncthreads();
    }

    // ping-pong h planes
    u16* th = hiOut; hiOut = hiIn; hiIn = th;
    u16* tl = loOut; loOut = loIn; loIn = tl;
  }
}

// ---------------------------------------------------------------- launch ----
extern "C" void kernel_launch(void* const* d_in, const int* in_sizes, int n_in,
                              void* d_out, int out_size, void* d_ws, size_t ws_size,
                              hipStream_t stream) {
  const int* src = (const int*)d_in[0];
  const int* tgt = (const int*)d_in[1];
  const float* emb = (const float*)d_in[2];
  const float* dec_emb = (const float*)d_in[3];
  const float* e_wih = (const float*)d_in[4];
  const float* e_whh = (const float*)d_in[5];
  const float* e_bih = (const float*)d_in[6];
  const float* e_bhh = (const float*)d_in[7];
  const float* d_wih = (const float*)d_in[8];
  const float* d_whh = (const float*)d_in[9];
  const float* d_bih = (const float*)d_in[10];
  const float* d_bhh = (const float*)d_in[11];
  const float* fc_w = (const float*)d_in[12];
  const float* fc_b = (const float*)d_in[13];
  float* out = (float*)d_out;

  char* ws = (char*)d_ws;
  u16* WhiE = (u16*)(ws + 0);             // 3,145,728
  u16* WloE = (u16*)(ws + 3145728);       // 3,145,728
  u16* WhiD = (u16*)(ws + 6291456);       // 3,145,728
  u16* WloD = (u16*)(ws + 9437184);       // 3,145,728
  float* bcE = (float*)(ws + 12582912);   // 8,192
  float* bcD = (float*)(ws + 12591104);   // 8,192
  u16* eHiE = (u16*)(ws + 12599296);      // 65,536
  u16* eLoE = (u16*)(ws + 12664832);      // 65,536
  u16* eHiD = (u16*)(ws + 12730368);      // 65,536
  u16* eLoD = (u16*)(ws + 12795904);      // 65,536
  float* fwT = (float*)(ws + 12861440);   // 262,144
  float* fcb = (float*)(ws + 13123584);   // 512
  u16* hHiA = (u16*)(ws + 13124096);      // 1,048,576
  u16* hLoA = (u16*)(ws + 14172672);      // 1,048,576
  u16* hHiB = (u16*)(ws + 15221248);      // 1,048,576
  u16* hLoB = (u16*)(ws + 16269824);      // 1,048,576
  unsigned* cnt = (unsigned*)(ws + 17318400);  // 256 B  (total ~17.3 MB)

  prep_m<<<1024, 256, 0, stream>>>(e_wih, e_whh, e_bih, e_bhh,
                                   d_wih, d_whh, d_bih, d_bhh,
                                   emb, dec_emb, fc_w, fc_b,
                                   WhiE, WloE, WhiD, WloD, bcE, bcD,
                                   eHiE, eLoE, eHiD, eLoD, fwT, fcb,
                                   hHiA, hLoA, cnt, out);

  seq_persist<<<NBLK, 256, 0, stream>>>(eHiE, eLoE, eHiD, eLoD, src, tgt,
                                        WhiE, WloE, WhiD, WloD, bcE, bcD,
                                        fwT, fcb, hHiA, hLoA, hHiB, hLoB,
                                        out, cnt);
}